// Round 4
// baseline (175.207 us; speedup 1.0000x reference)
//
#include <hip/hip_runtime.h>
#include <hip/hip_bf16.h>
#include <math.h>

#define NB 32768
#define DD 128
#define HH 512
#define EE 16

typedef __attribute__((ext_vector_type(8))) short short8;
typedef __attribute__((ext_vector_type(4))) float f32x4;

__device__ __forceinline__ unsigned int pk_bf16(float a, float b) {
  float2 t; t.x = a; t.y = b;
  __hip_bfloat162 h = __float22bfloat162_rn(t);
  union { __hip_bfloat162 h; unsigned int u; } cv; cv.h = h;
  return cv.u;
}

// Abramowitz-Stegun 7.1.26 erf, |eps| <= 1.5e-7 (far below bf16 noise)
__device__ __forceinline__ float gelu_f(float v) {
  float z = v * 0.70710678118654752f;
  float a = fabsf(z);
  float t = 1.0f / (1.0f + 0.3275911f * a);
  float y = t * (0.254829592f + t * (-0.284496736f + t * (1.421413741f +
            t * (-1.453152027f + t * 1.061405429f))));
  float r = 1.0f - y * __expf(-a * a);
  r = z < 0.0f ? -r : r;
  return 0.5f * v * (1.0f + r);
}

// ---------------- fused prep: gate (blocks 0..255) + weight transpose (256..767) ----
__global__ __launch_bounds__(256) void prep_kernel(
    const float* __restrict__ x, const float* __restrict__ w1,
    const float* __restrict__ w2, const float* __restrict__ wg,
    const float* __restrict__ bg,
    unsigned short* __restrict__ w1T, unsigned short* __restrict__ w2T,
    int* __restrict__ counts, int* __restrict__ rows) {
  __shared__ float swg[DD * EE];
  __shared__ int lcnt[EE], gbase[EE], lslot[128], lexp[128];
  __shared__ float sT[64 * 65];   // stride 65: conflict-free transposed reads

  int tid = threadIdx.x;
  int bid = blockIdx.x;

  if (bid < 256) {
    // ---- gate: 128 rows/block, 2 threads/row (d-split), fp64 accumulate ----
    if (tid < EE) lcnt[tid] = 0;
    for (int i = tid; i < DD * EE; i += 256) swg[i] = wg[i];
    __syncthreads();

    int r = tid >> 1, half = tid & 1;
    int row = bid * 128 + r;
    double acc[EE];
    #pragma unroll
    for (int e2 = 0; e2 < EE; ++e2) acc[e2] = 0.0;

    const f32x4* xp = (const f32x4*)(x + (size_t)row * DD + half * 64);
    #pragma unroll 2
    for (int i = 0; i < 16; ++i) {
      f32x4 v = xp[i];
      #pragma unroll
      for (int c = 0; c < 4; ++c) {
        double xv = (double)v[c];
        int d = half * 64 + i * 4 + c;
        #pragma unroll
        for (int e2 = 0; e2 < EE; ++e2)
          acc[e2] += xv * (double)swg[d * EE + e2];   // lane-uniform addr -> broadcast
      }
    }

    // merge halves (lane pair), add bg, argmax (strict > keeps lowest idx)
    int ge = 0; double bv = -1.0e300;
    #pragma unroll
    for (int e2 = 0; e2 < EE; ++e2) {
      double o = __shfl_xor(acc[e2], 1);
      double t = acc[e2] + o + (double)bg[e2];
      if (t > bv) { bv = t; ge = e2; }
    }
    if (half == 0) {
      lslot[r] = atomicAdd(&lcnt[ge], 1);
      lexp[r] = ge;
    }
    __syncthreads();
    if (tid < EE && lcnt[tid] > 0)
      gbase[tid] = atomicAdd(&counts[tid], lcnt[tid]);  // 16 global atomics/block
    __syncthreads();
    if (half == 0) {
      int e2 = lexp[r];
      rows[e2 * NB + gbase[e2] + lslot[r]] = row;
    }
  } else {
    // ---- transpose+cast: 64x64 fp32 tile -> bf16 transposed ----
    int tb = bid - 256;
    const float* src; unsigned short* dst; int sstride, dstride;
    if (tb < 256) {  // w1 (E,D,H) -> w1T (E,H,D)
      int e2 = tb >> 4, t = tb & 15;
      int d0 = (t >> 3) * 64, h0 = (t & 7) * 64;
      src = w1 + ((size_t)e2 * DD + d0) * HH + h0; sstride = HH;
      dst = w1T + (size_t)e2 * HH * DD + (size_t)h0 * DD + d0; dstride = DD;
    } else {         // w2 (E,H,D) -> w2T (E,D,H)
      int t2 = tb - 256;
      int e2 = t2 >> 4, t = t2 & 15;
      int h0 = (t >> 1) * 64, d0 = (t & 1) * 64;
      src = w2 + ((size_t)e2 * HH + h0) * DD + d0; sstride = DD;
      dst = w2T + (size_t)e2 * DD * HH + (size_t)d0 * HH + h0; dstride = HH;
    }
    int rr = tid >> 4, c4 = tid & 15;
    #pragma unroll
    for (int j = 0; j < 4; ++j) {
      int sr = rr + 16 * j;
      f32x4 v = *(const f32x4*)(src + (size_t)sr * sstride + c4 * 4);
      #pragma unroll
      for (int i = 0; i < 4; ++i) sT[sr * 65 + c4 * 4 + i] = v[i];
    }
    __syncthreads();
    #pragma unroll
    for (int j = 0; j < 4; ++j) {
      int R = rr + 16 * j;
      float f0 = sT[(4 * c4 + 0) * 65 + R];
      float f1 = sT[(4 * c4 + 1) * 65 + R];
      float f2 = sT[(4 * c4 + 2) * 65 + R];
      float f3 = sT[(4 * c4 + 3) * 65 + R];
      uint2 pkd; pkd.x = pk_bf16(f0, f1); pkd.y = pk_bf16(f2, f3);
      *(uint2*)(dst + (size_t)R * dstride + 4 * c4) = pkd;
    }
  }
}

// ---------------- grouped expert GEMM, flipped orientation ----------------
// Wave owns 32 rows. X frags in registers; weights streamed from global (L2);
// H per-wave-private in LDS (packed writes, no barriers anywhere).
__global__ __launch_bounds__(256) void moe_gemm(
    const float* __restrict__ x, const unsigned short* __restrict__ w1T,
    const unsigned short* __restrict__ w2T, const int* __restrict__ counts,
    const int* __restrict__ rows, float* __restrict__ out) {
  int e = blockIdx.y;
  int cnt = counts[e];
  int base = blockIdx.x * 128;
  if (base >= cnt) return;

  __shared__ unsigned short sH[4][32][72];  // [wave][m][h64 pad->72] 18.4 KB

  int tid = threadIdx.x;
  int wv = tid >> 6, l = tid & 63;
  int lm = l & 15, q = l >> 4;

  int m0 = base + wv * 32;
  int i0 = m0 + lm;      int ci0 = i0 < cnt ? i0 : cnt - 1;
  int i1 = m0 + 16 + lm; int ci1 = i1 < cnt ? i1 : cnt - 1;
  int grow0 = rows[e * NB + ci0];
  int grow1 = rows[e * NB + ci1];

  // X fragments: xf[nt][ks] = x[row nt*16+lm][d = ks*32+q*8 .. +7] as bf16
  short8 xf[2][4];
  #pragma unroll
  for (int nt = 0; nt < 2; ++nt) {
    const float* xr = x + (size_t)(nt ? grow1 : grow0) * DD;
    #pragma unroll
    for (int ks = 0; ks < 4; ++ks) {
      const f32x4* p = (const f32x4*)(xr + ks * 32 + q * 8);
      f32x4 v0 = p[0], v1 = p[1];
      union { short8 s; unsigned int u[4]; } pk;
      pk.u[0] = pk_bf16(v0[0], v0[1]);
      pk.u[1] = pk_bf16(v0[2], v0[3]);
      pk.u[2] = pk_bf16(v1[0], v1[1]);
      pk.u[3] = pk_bf16(v1[2], v1[3]);
      xf[nt][ks] = pk.s;
    }
  }

  f32x4 acc[2][8];  // out^T: lane holds out[m=nt*16+lm][d = dt*16+q*4+r]
  #pragma unroll
  for (int nt = 0; nt < 2; ++nt)
    #pragma unroll
    for (int dt = 0; dt < 8; ++dt) acc[nt][dt] = (f32x4){0.f, 0.f, 0.f, 0.f};

  const unsigned short* w1e = w1T + (size_t)e * HH * DD;
  const unsigned short* w2e = w2T + (size_t)e * DD * HH;

  for (int hc = 0; hc < 8; ++hc) {
    int h0 = hc * 64;
    // GEMM1': H^T tile; A = w1T rows (global), B = xf (registers)
    #pragma unroll
    for (int ht = 0; ht < 4; ++ht) {
      f32x4 ha = (f32x4){0.f, 0.f, 0.f, 0.f};
      f32x4 hb = (f32x4){0.f, 0.f, 0.f, 0.f};
      const unsigned short* wr = w1e + (size_t)(h0 + ht * 16 + lm) * DD + q * 8;
      #pragma unroll
      for (int ks = 0; ks < 4; ++ks) {
        short8 a = *(const short8*)(wr + ks * 32);
        ha = __builtin_amdgcn_mfma_f32_16x16x32_bf16(a, xf[0][ks], ha, 0, 0, 0);
        hb = __builtin_amdgcn_mfma_f32_16x16x32_bf16(a, xf[1][ks], hb, 0, 0, 0);
      }
      // lane holds H[m][h = ht*16 + q*4 + r]: gelu, pack 4 bf16, one 8B write
      uint2 wa, wb;
      wa.x = pk_bf16(gelu_f(ha[0]), gelu_f(ha[1]));
      wa.y = pk_bf16(gelu_f(ha[2]), gelu_f(ha[3]));
      wb.x = pk_bf16(gelu_f(hb[0]), gelu_f(hb[1]));
      wb.y = pk_bf16(gelu_f(hb[2]), gelu_f(hb[3]));
      *(uint2*)&sH[wv][lm][ht * 16 + q * 4] = wa;
      *(uint2*)&sH[wv][16 + lm][ht * 16 + q * 4] = wb;
    }
    // GEMM2' partial: A = w2T rows (global), B = H from private LDS
    #pragma unroll
    for (int ks = 0; ks < 2; ++ks) {
      short8 b0 = *(const short8*)&sH[wv][lm][ks * 32 + q * 8];
      short8 b1 = *(const short8*)&sH[wv][16 + lm][ks * 32 + q * 8];
      const unsigned short* wr2 = w2e + (size_t)lm * HH + h0 + ks * 32 + q * 8;
      #pragma unroll
      for (int dt = 0; dt < 8; ++dt) {
        short8 a = *(const short8*)(wr2 + (size_t)dt * 16 * HH);
        acc[0][dt] = __builtin_amdgcn_mfma_f32_16x16x32_bf16(a, b0, acc[0][dt], 0, 0, 0);
        acc[1][dt] = __builtin_amdgcn_mfma_f32_16x16x32_bf16(a, b1, acc[1][dt], 0, 0, 0);
      }
    }
  }

  // epilogue: float4 stores, one row per lane per nt
  #pragma unroll
  for (int nt = 0; nt < 2; ++nt) {
    int mi = m0 + nt * 16 + lm;
    if (mi < cnt) {
      int grow = nt ? grow1 : grow0;
      float* op = out + (size_t)grow * DD + q * 4;
      #pragma unroll
      for (int dt = 0; dt < 8; ++dt)
        *(f32x4*)(op + dt * 16) = acc[nt][dt];
    }
  }
}

extern "C" void kernel_launch(void* const* d_in, const int* in_sizes, int n_in,
                              void* d_out, int out_size, void* d_ws, size_t ws_size,
                              hipStream_t stream) {
  const float* x  = (const float*)d_in[0];
  const float* w1 = (const float*)d_in[1];
  const float* w2 = (const float*)d_in[2];
  const float* wg = (const float*)d_in[3];
  const float* bg = (const float*)d_in[4];
  float* out = (float*)d_out;

  // ws: [0,64) counts | [1024, +2MB) rows[16][32768] | w1T 2MB | w2T 2MB
  int* counts = (int*)d_ws;
  int* rows   = (int*)((char*)d_ws + 1024);
  unsigned short* w1T = (unsigned short*)((char*)d_ws + 1024 + (size_t)EE * NB * 4);
  unsigned short* w2T = w1T + (size_t)EE * HH * DD;

  hipMemsetAsync(d_ws, 0, 64, stream);
  hipLaunchKernelGGL(prep_kernel, dim3(768), dim3(256), 0, stream,
                     x, w1, w2, wg, bg, w1T, w2T, counts, rows);
  hipLaunchKernelGGL(moe_gemm, dim3(NB / 128, EE), dim3(256), 0, stream,
                     x, w1T, w2T, counts, rows, out);
}

// Round 5
// 146.416 us; speedup vs baseline: 1.1966x; 1.1966x over previous
//
#include <hip/hip_runtime.h>
#include <hip/hip_bf16.h>
#include <math.h>

#define NB 32768
#define DD 128
#define HH 512
#define EE 16

typedef __attribute__((ext_vector_type(8))) short short8;
typedef __attribute__((ext_vector_type(4))) float f32x4;

__device__ __forceinline__ unsigned int pk_bf16(float a, float b) {
  float2 t; t.x = a; t.y = b;
  __hip_bfloat162 h = __float22bfloat162_rn(t);
  union { __hip_bfloat162 h; unsigned int u; } cv; cv.h = h;
  return cv.u;
}

// Abramowitz-Stegun 7.1.26 erf, |eps| <= 1.5e-7 (far below bf16 noise)
__device__ __forceinline__ float gelu_f(float v) {
  float z = v * 0.70710678118654752f;
  float a = fabsf(z);
  float t = 1.0f / (1.0f + 0.3275911f * a);
  float y = t * (0.254829592f + t * (-0.284496736f + t * (1.421413741f +
            t * (-1.453152027f + t * 1.061405429f))));
  float r = 1.0f - y * __expf(-a * a);
  r = z < 0.0f ? -r : r;
  return 0.5f * v * (1.0f + r);
}

// ---------------- fused prep: gate (blocks 0..255) + weight transpose (256..767) ----
__global__ __launch_bounds__(256) void prep_kernel(
    const float* __restrict__ x, const float* __restrict__ w1,
    const float* __restrict__ w2, const float* __restrict__ wg,
    const float* __restrict__ bg,
    unsigned short* __restrict__ w1T, unsigned short* __restrict__ w2T,
    int* __restrict__ counts, int* __restrict__ rows) {
  __shared__ double swg[DD * EE];   // 16 KB fp64 gate weights
  __shared__ int lcnt[EE], gbase[EE], lslot[128], lexp[128];
  __shared__ float sT[64 * 65];     // transpose tile

  int tid = threadIdx.x;
  int bid = blockIdx.x;

  if (bid < 256) {
    // ---- gate: 128 rows/block, 2 threads/row (d-halves), fp64, batched loads ----
    if (tid < EE) lcnt[tid] = 0;
    for (int i = tid; i < DD * EE; i += 256) swg[i] = (double)wg[i];
    __syncthreads();

    int r = tid >> 1, half = tid & 1;
    int row = bid * 128 + r;
    const f32x4* xp = (const f32x4*)(x + (size_t)row * DD + half * 64);

    double acc[EE];
    #pragma unroll
    for (int e2 = 0; e2 < EE; ++e2) acc[e2] = 0.0;

    const double* wbase = swg + half * 64 * EE;  // this half's d-range
    #pragma unroll
    for (int batch = 0; batch < 2; ++batch) {
      f32x4 xv[8];
      #pragma unroll
      for (int i = 0; i < 8; ++i) xv[i] = xp[batch * 8 + i];  // 8 indep loads, one wait
      #pragma unroll
      for (int i = 0; i < 8; ++i) {
        #pragma unroll
        for (int c = 0; c < 4; ++c) {
          double xd = (double)xv[i][c];
          const double* wrow = wbase + (batch * 32 + i * 4 + c) * EE;
          #pragma unroll
          for (int ee = 0; ee < EE; ee += 2) {
            double2 w = *(const double2*)(wrow + ee);  // b128 broadcast read
            acc[ee]     += xd * w.x;
            acc[ee + 1] += xd * w.y;
          }
        }
      }
    }

    // merge halves (lane pair), add bg, argmax (strict > keeps lowest idx)
    int ge = 0; double bv = -1.0e300;
    #pragma unroll
    for (int e2 = 0; e2 < EE; ++e2) {
      double o = __shfl_xor(acc[e2], 1);
      double t = acc[e2] + o + (double)bg[e2];
      if (t > bv) { bv = t; ge = e2; }
    }
    if (half == 0) {
      lslot[r] = atomicAdd(&lcnt[ge], 1);
      lexp[r] = ge;
    }
    __syncthreads();
    if (tid < EE && lcnt[tid] > 0)
      gbase[tid] = atomicAdd(&counts[tid], lcnt[tid]);  // 16 global atomics/block
    __syncthreads();
    if (half == 0) {
      int e2 = lexp[r];
      rows[e2 * NB + gbase[e2] + lslot[r]] = row;
    }
  } else {
    // ---- transpose+cast: 64x64 fp32 tile -> bf16 transposed (verified R4) ----
    int tb = bid - 256;
    const float* src; unsigned short* dst; int sstride, dstride;
    if (tb < 256) {  // w1 (E,D,H) -> w1T (E,H,D)
      int e2 = tb >> 4, t = tb & 15;
      int d0 = (t >> 3) * 64, h0 = (t & 7) * 64;
      src = w1 + ((size_t)e2 * DD + d0) * HH + h0; sstride = HH;
      dst = w1T + (size_t)e2 * HH * DD + (size_t)h0 * DD + d0; dstride = DD;
    } else {         // w2 (E,H,D) -> w2T (E,D,H)
      int t2 = tb - 256;
      int e2 = t2 >> 4, t = t2 & 15;
      int h0 = (t >> 1) * 64, d0 = (t & 1) * 64;
      src = w2 + ((size_t)e2 * HH + h0) * DD + d0; sstride = DD;
      dst = w2T + (size_t)e2 * DD * HH + (size_t)d0 * HH + h0; dstride = HH;
    }
    int rr = tid >> 4, c4 = tid & 15;
    #pragma unroll
    for (int j = 0; j < 4; ++j) {
      int sr = rr + 16 * j;
      f32x4 v = *(const f32x4*)(src + (size_t)sr * sstride + c4 * 4);
      #pragma unroll
      for (int i = 0; i < 4; ++i) sT[sr * 65 + c4 * 4 + i] = v[i];
    }
    __syncthreads();
    #pragma unroll
    for (int j = 0; j < 4; ++j) {
      int R = rr + 16 * j;
      float f0 = sT[(4 * c4 + 0) * 65 + R];
      float f1 = sT[(4 * c4 + 1) * 65 + R];
      float f2 = sT[(4 * c4 + 2) * 65 + R];
      float f3 = sT[(4 * c4 + 3) * 65 + R];
      uint2 pkd; pkd.x = pk_bf16(f0, f1); pkd.y = pk_bf16(f2, f3);
      *(uint2*)(dst + (size_t)R * dstride + 4 * c4) = pkd;
    }
  }
}

// ---------------- grouped expert GEMM: flipped MFMA + LDS-staged weights ----------
// Wave owns 32 rows; X frags in registers; weights staged to LDS per 64-h chunk;
// H per-wave-private packed LDS (no conflicts). TM=128 -> 256 surviving blocks.
__global__ __launch_bounds__(256) void moe_gemm(
    const float* __restrict__ x, const unsigned short* __restrict__ w1T,
    const unsigned short* __restrict__ w2T, const int* __restrict__ counts,
    const int* __restrict__ rows, float* __restrict__ out) {
  int e = blockIdx.y;
  int cnt = counts[e];
  int base = blockIdx.x * 128;
  if (base >= cnt) return;

  __shared__ unsigned short sW1[64][136];   // w1T chunk [h_local][d], pad 8
  __shared__ unsigned short sW2[DD][72];    // w2T chunk [d][h_local], pad 8
  __shared__ unsigned short sH[4][32][72];  // per-wave hidden [m][h_local]

  int tid = threadIdx.x;
  int wv = tid >> 6, l = tid & 63;
  int lm = l & 15, q = l >> 4;

  int m0 = base + wv * 32;
  int i0 = m0 + lm;      int ci0 = i0 < cnt ? i0 : cnt - 1;
  int i1 = m0 + 16 + lm; int ci1 = i1 < cnt ? i1 : cnt - 1;
  int grow0 = rows[e * NB + ci0];
  int grow1 = rows[e * NB + ci1];

  // X fragments in registers: xf[nt][ks] = x[row][d = ks*32+q*8 .. +7] bf16
  short8 xf[2][4];
  #pragma unroll
  for (int nt = 0; nt < 2; ++nt) {
    const float* xr = x + (size_t)(nt ? grow1 : grow0) * DD;
    #pragma unroll
    for (int ks = 0; ks < 4; ++ks) {
      const f32x4* p = (const f32x4*)(xr + ks * 32 + q * 8);
      f32x4 v0 = p[0], v1 = p[1];
      union { short8 s; unsigned int u[4]; } pk;
      pk.u[0] = pk_bf16(v0[0], v0[1]);
      pk.u[1] = pk_bf16(v0[2], v0[3]);
      pk.u[2] = pk_bf16(v1[0], v1[1]);
      pk.u[3] = pk_bf16(v1[2], v1[3]);
      xf[nt][ks] = pk.s;
    }
  }

  f32x4 acc[2][8];  // lane holds out[m = nt*16+lm][d = dt*16 + q*4 + r]
  #pragma unroll
  for (int nt = 0; nt < 2; ++nt)
    #pragma unroll
    for (int dt = 0; dt < 8; ++dt) acc[nt][dt] = (f32x4){0.f, 0.f, 0.f, 0.f};

  const unsigned short* w1e = w1T + (size_t)e * HH * DD;
  const unsigned short* w2e = w2T + (size_t)e * DD * HH;

  for (int hc = 0; hc < 8; ++hc) {
    int h0 = hc * 64;
    // stage w1T chunk: 64 rows x 128 d = 16 KB contiguous
    {
      const uint4* src = (const uint4*)(w1e + (size_t)h0 * DD);
      #pragma unroll
      for (int i = 0; i < 4; ++i) {
        int u = tid + i * 256;
        int r = u >> 4, c = u & 15;
        *(uint4*)&sW1[r][c * 8] = src[u];
      }
    }
    // stage w2T chunk: 128 d-rows x 64 h-cols
    {
      #pragma unroll
      for (int i = 0; i < 4; ++i) {
        int u = tid + i * 256;
        int r = u >> 3, c = u & 7;
        const uint4* src = (const uint4*)(w2e + (size_t)r * HH + h0);
        *(uint4*)&sW2[r][c * 8] = src[c];
      }
    }
    __syncthreads();

    // GEMM1 (flipped): A = w1 frags from LDS, B = x register frags
    #pragma unroll
    for (int ht = 0; ht < 4; ++ht) {
      f32x4 ha = (f32x4){0.f, 0.f, 0.f, 0.f};
      f32x4 hb = (f32x4){0.f, 0.f, 0.f, 0.f};
      #pragma unroll
      for (int ks = 0; ks < 4; ++ks) {
        short8 a = *(const short8*)&sW1[ht * 16 + lm][ks * 32 + q * 8];
        ha = __builtin_amdgcn_mfma_f32_16x16x32_bf16(a, xf[0][ks], ha, 0, 0, 0);
        hb = __builtin_amdgcn_mfma_f32_16x16x32_bf16(a, xf[1][ks], hb, 0, 0, 0);
      }
      // lane holds H[m][h = ht*16 + q*4 + r]: gelu, pack, one 8B LDS write
      uint2 wa, wb;
      wa.x = pk_bf16(gelu_f(ha[0]), gelu_f(ha[1]));
      wa.y = pk_bf16(gelu_f(ha[2]), gelu_f(ha[3]));
      wb.x = pk_bf16(gelu_f(hb[0]), gelu_f(hb[1]));
      wb.y = pk_bf16(gelu_f(hb[2]), gelu_f(hb[3]));
      *(uint2*)&sH[wv][lm][ht * 16 + q * 4] = wa;
      *(uint2*)&sH[wv][16 + lm][ht * 16 + q * 4] = wb;
    }

    // GEMM2 (flipped): A = w2 frags from LDS, B = H frags from private LDS
    #pragma unroll
    for (int ks = 0; ks < 2; ++ks) {
      short8 b0 = *(const short8*)&sH[wv][lm][ks * 32 + q * 8];
      short8 b1 = *(const short8*)&sH[wv][16 + lm][ks * 32 + q * 8];
      #pragma unroll
      for (int dt = 0; dt < 8; ++dt) {
        short8 a = *(const short8*)&sW2[dt * 16 + lm][ks * 32 + q * 8];
        acc[0][dt] = __builtin_amdgcn_mfma_f32_16x16x32_bf16(a, b0, acc[0][dt], 0, 0, 0);
        acc[1][dt] = __builtin_amdgcn_mfma_f32_16x16x32_bf16(a, b1, acc[1][dt], 0, 0, 0);
      }
    }
    __syncthreads();  // protect sW1/sW2 before next staging
  }

  // epilogue: float4 stores
  #pragma unroll
  for (int nt = 0; nt < 2; ++nt) {
    int mi = m0 + nt * 16 + lm;
    if (mi < cnt) {
      int grow = nt ? grow1 : grow0;
      float* op = out + (size_t)grow * DD + q * 4;
      #pragma unroll
      for (int dt = 0; dt < 8; ++dt)
        *(f32x4*)(op + dt * 16) = acc[nt][dt];
    }
  }
}

extern "C" void kernel_launch(void* const* d_in, const int* in_sizes, int n_in,
                              void* d_out, int out_size, void* d_ws, size_t ws_size,
                              hipStream_t stream) {
  const float* x  = (const float*)d_in[0];
  const float* w1 = (const float*)d_in[1];
  const float* w2 = (const float*)d_in[2];
  const float* wg = (const float*)d_in[3];
  const float* bg = (const float*)d_in[4];
  float* out = (float*)d_out;

  // ws: [0,64) counts | [1024, +2MB) rows[16][32768] | w1T 2MB | w2T 2MB
  int* counts = (int*)d_ws;
  int* rows   = (int*)((char*)d_ws + 1024);
  unsigned short* w1T = (unsigned short*)((char*)d_ws + 1024 + (size_t)EE * NB * 4);
  unsigned short* w2T = w1T + (size_t)EE * HH * DD;

  hipMemsetAsync(d_ws, 0, 64, stream);
  hipLaunchKernelGGL(prep_kernel, dim3(768), dim3(256), 0, stream,
                     x, w1, w2, wg, bg, w1T, w2T, counts, rows);
  hipLaunchKernelGGL(moe_gemm, dim3(NB / 128, EE), dim3(256), 0, stream,
                     x, w1T, w2T, counts, rows, out);
}

// Round 7
// 144.159 us; speedup vs baseline: 1.2154x; 1.0157x over previous
//
#include <hip/hip_runtime.h>
#include <hip/hip_bf16.h>
#include <math.h>

#define NB 32768
#define DD 128
#define HH 512
#define EE 16

typedef __attribute__((ext_vector_type(8))) short short8;
typedef __attribute__((ext_vector_type(4))) float f32x4;

__device__ __forceinline__ unsigned int pk_bf16(float a, float b) {
  float2 t; t.x = a; t.y = b;
  __hip_bfloat162 h = __float22bfloat162_rn(t);
  union { __hip_bfloat162 h; unsigned int u; } cv; cv.h = h;
  return cv.u;
}

// Abramowitz-Stegun 7.1.26 erf, |eps| <= 1.5e-7 (far below bf16 noise)
__device__ __forceinline__ float gelu_f(float v) {
  float z = v * 0.70710678118654752f;
  float a = fabsf(z);
  float t = 1.0f / (1.0f + 0.3275911f * a);
  float y = t * (0.254829592f + t * (-0.284496736f + t * (1.421413741f +
            t * (-1.453152027f + t * 1.061405429f))));
  float r = 1.0f - y * __expf(-a * a);
  r = z < 0.0f ? -r : r;
  return 0.5f * v * (1.0f + r);
}

// ---------------- fused prep: gate (bid<512) + weight transpose (512..1023) ----
// Gate: wg held in REGISTERS (lane = expert-pair x d-sixteenth), rows looped.
// No per-row weight reload -> no load-latency chains (R1-R5 failure mode).
__global__ __launch_bounds__(256, 3) void prep_kernel(
    const float* __restrict__ x, const float* __restrict__ w1,
    const float* __restrict__ w2, const float* __restrict__ wg,
    const float* __restrict__ bg,
    unsigned short* __restrict__ w1T, unsigned short* __restrict__ w2T,
    int* __restrict__ counts, int* __restrict__ rows) {
  __shared__ __align__(16) char smem[34816];

  int tid = threadIdx.x;
  int bid = blockIdx.x;

  if (bid < 512) {
    float (*sx)[132] = (float(*)[132])smem;      // 64 rows x 128 (pad 132), 33.8 KB
    int* lslot = (int*)(smem + 33792);
    int* lexp  = (int*)(smem + 34048);
    int* lcnt  = (int*)(smem + 34304);
    int* gbase = (int*)(smem + 34368);

    int base = bid * 64;
    if (tid < EE) lcnt[tid] = 0;
    {  // stage 64 x-rows coalesced: 4 threads/row, 32 cols each
      int r = tid >> 2, c0 = (tid & 3) * 32;
      const f32x4* src = (const f32x4*)(x + (size_t)(base + r) * DD + c0);
      #pragma unroll
      for (int i = 0; i < 8; ++i)
        *(f32x4*)&sx[r][c0 + i * 4] = src[i];
    }

    int wv = tid >> 6, l = tid & 63;
    int ep = l & 7;        // expert pair: experts {2ep, 2ep+1}
    int ds = l >> 3;       // d-slice: d in [ds*16, ds*16+16)

    // wg slice in registers: loaded ONCE (fp64 exact, as validated R1-R5)
    double wr0[16], wr1[16];
    {
      const float* wp = wg + (ds * 16) * EE + 2 * ep;
      #pragma unroll
      for (int i = 0; i < 16; ++i) {
        float2 w2v = *(const float2*)(wp + i * EE);
        wr0[i] = (double)w2v.x; wr1[i] = (double)w2v.y;
      }
    }
    double bg0 = (double)bg[2 * ep], bg1 = (double)bg[2 * ep + 1];
    __syncthreads();

    // each wave handles 16 rows; per row: broadcast x from LDS, 32 fp64 FMA
    for (int rr = 0; rr < 16; ++rr) {
      int row = wv * 16 + rr;
      double a0 = 0.0, a1 = 0.0;
      #pragma unroll
      for (int i = 0; i < 4; ++i) {
        f32x4 xv = *(const f32x4*)&sx[row][ds * 16 + i * 4];  // 8-way broadcast
        #pragma unroll
        for (int c = 0; c < 4; ++c) {
          double xd = (double)xv[c];
          a0 += xd * wr0[i * 4 + c];
          a1 += xd * wr1[i * 4 + c];
        }
      }
      // reduce over the 8 d-slices (partners share ep)
      #pragma unroll
      for (int off = 8; off < 64; off <<= 1) {
        a0 += __shfl_xor(a0, off);
        a1 += __shfl_xor(a1, off);
      }
      a0 += bg0; a1 += bg1;
      // within-lane argmax of the expert pair (tie -> lower idx)
      double bv = a0; int be = 2 * ep;
      if (a1 > a0) { bv = a1; be = 2 * ep + 1; }
      // butterfly argmax over the 8 expert-pairs
      #pragma unroll
      for (int off = 1; off < 8; off <<= 1) {
        double ov = __shfl_xor(bv, off);
        int oe = __shfl_xor(be, off);
        if (ov > bv || (ov == bv && oe < be)) { bv = ov; be = oe; }
      }
      if (l == 0) {
        lslot[row] = atomicAdd(&lcnt[be], 1);
        lexp[row] = be;
      }
    }
    __syncthreads();
    if (tid < EE && lcnt[tid] > 0)
      gbase[tid] = atomicAdd(&counts[tid * 16], lcnt[tid]);  // padded counters
    __syncthreads();
    if (tid < 64) {
      int e2 = lexp[tid];
      rows[e2 * NB + gbase[e2] + lslot[tid]] = base + tid;
    }
  } else {
    // ---- transpose+cast: 64x64 fp32 tile -> bf16 transposed (verified R4/R5) ----
    float* sT = (float*)smem;   // [64][65] = 16.6 KB
    int tb = bid - 512;
    const float* src; unsigned short* dst; int sstride, dstride;
    if (tb < 256) {  // w1 (E,D,H) -> w1T (E,H,D)
      int e2 = tb >> 4, t = tb & 15;
      int d0 = (t >> 3) * 64, h0 = (t & 7) * 64;
      src = w1 + ((size_t)e2 * DD + d0) * HH + h0; sstride = HH;
      dst = w1T + (size_t)e2 * HH * DD + (size_t)h0 * DD + d0; dstride = DD;
    } else {         // w2 (E,H,D) -> w2T (E,D,H)
      int t2 = tb - 256;
      int e2 = t2 >> 4, t = t2 & 15;
      int h0 = (t >> 1) * 64, d0 = (t & 1) * 64;
      src = w2 + ((size_t)e2 * HH + h0) * DD + d0; sstride = DD;
      dst = w2T + (size_t)e2 * DD * HH + (size_t)d0 * HH + h0; dstride = HH;
    }
    int rr = tid >> 4, c4 = tid & 15;
    #pragma unroll
    for (int j = 0; j < 4; ++j) {
      int sr = rr + 16 * j;
      f32x4 v = *(const f32x4*)(src + (size_t)sr * sstride + c4 * 4);
      #pragma unroll
      for (int i = 0; i < 4; ++i) sT[sr * 65 + c4 * 4 + i] = v[i];
    }
    __syncthreads();
    #pragma unroll
    for (int j = 0; j < 4; ++j) {
      int R = rr + 16 * j;
      float f0 = sT[(4 * c4 + 0) * 65 + R];
      float f1 = sT[(4 * c4 + 1) * 65 + R];
      float f2 = sT[(4 * c4 + 2) * 65 + R];
      float f3 = sT[(4 * c4 + 3) * 65 + R];
      uint2 pkd; pkd.x = pk_bf16(f0, f1); pkd.y = pk_bf16(f2, f3);
      *(uint2*)(dst + (size_t)R * dstride + 4 * c4) = pkd;
    }
  }
}

// ---------------- grouped expert GEMM: TM=64, 4 waves x 16 rows ----------------
// Flipped MFMA; X frags in registers; weights LDS-staged; per-wave-private sH.
__global__ __launch_bounds__(256, 3) void moe_gemm(
    const float* __restrict__ x, const unsigned short* __restrict__ w1T,
    const unsigned short* __restrict__ w2T, const int* __restrict__ counts,
    const int* __restrict__ rows, float* __restrict__ out) {
  int e = blockIdx.y;
  int cnt = counts[e * 16];
  int base = blockIdx.x * 64;
  if (base >= cnt) return;

  __shared__ unsigned short sW1[64][136];   // w1T chunk [h_local][d], pad 8
  __shared__ unsigned short sW2[DD][72];    // w2T chunk [d][h_local], pad 8
  __shared__ unsigned short sH[4][16][72];  // per-wave hidden [m][h_local]

  int tid = threadIdx.x;
  int wv = tid >> 6, l = tid & 63;
  int lm = l & 15, q = l >> 4;

  int i0 = base + wv * 16 + lm;
  int ci0 = i0 < cnt ? i0 : cnt - 1;
  int grow = rows[e * NB + ci0];

  // X fragments in registers: xf[ks] = x[row][d = ks*32+q*8 .. +7] bf16
  short8 xf[4];
  {
    const float* xr = x + (size_t)grow * DD;
    #pragma unroll
    for (int ks = 0; ks < 4; ++ks) {
      const f32x4* p = (const f32x4*)(xr + ks * 32 + q * 8);
      f32x4 v0 = p[0], v1 = p[1];
      union { short8 s; unsigned int u[4]; } pk;
      pk.u[0] = pk_bf16(v0[0], v0[1]);
      pk.u[1] = pk_bf16(v0[2], v0[3]);
      pk.u[2] = pk_bf16(v1[0], v1[1]);
      pk.u[3] = pk_bf16(v1[2], v1[3]);
      xf[ks] = pk.s;
    }
  }

  f32x4 acc[8];  // lane holds out[m=lm][d = dt*16 + q*4 + r]
  #pragma unroll
  for (int dt = 0; dt < 8; ++dt) acc[dt] = (f32x4){0.f, 0.f, 0.f, 0.f};

  const unsigned short* w1e = w1T + (size_t)e * HH * DD;
  const unsigned short* w2e = w2T + (size_t)e * DD * HH;

  for (int hc = 0; hc < 8; ++hc) {
    int h0 = hc * 64;
    {  // stage w1T chunk: 64 h-rows x 128 d = 16 KB contiguous
      const uint4* src = (const uint4*)(w1e + (size_t)h0 * DD);
      #pragma unroll
      for (int i = 0; i < 4; ++i) {
        int u = tid + i * 256;
        int r = u >> 4, c = u & 15;
        *(uint4*)&sW1[r][c * 8] = src[u];
      }
    }
    {  // stage w2T chunk: 128 d-rows x 64 h-cols
      #pragma unroll
      for (int i = 0; i < 4; ++i) {
        int u = tid + i * 256;
        int r = u >> 3, c = u & 7;
        const uint4* src = (const uint4*)(w2e + (size_t)r * HH + h0);
        *(uint4*)&sW2[r][c * 8] = src[c];
      }
    }
    __syncthreads();

    // GEMM1 (flipped): A = w1 frags from LDS, B = x register frags
    #pragma unroll
    for (int ht = 0; ht < 4; ++ht) {
      f32x4 ha = (f32x4){0.f, 0.f, 0.f, 0.f};
      #pragma unroll
      for (int ks = 0; ks < 4; ++ks) {
        short8 a = *(const short8*)&sW1[ht * 16 + lm][ks * 32 + q * 8];
        ha = __builtin_amdgcn_mfma_f32_16x16x32_bf16(a, xf[ks], ha, 0, 0, 0);
      }
      // lane holds H[m=lm][h = ht*16 + q*4 + r]: gelu, pack, one 8B LDS write
      uint2 wa;
      wa.x = pk_bf16(gelu_f(ha[0]), gelu_f(ha[1]));
      wa.y = pk_bf16(gelu_f(ha[2]), gelu_f(ha[3]));
      *(uint2*)&sH[wv][lm][ht * 16 + q * 4] = wa;
    }

    // GEMM2 (flipped): A = w2 frags from LDS, B = H frags from private LDS
    #pragma unroll
    for (int ks = 0; ks < 2; ++ks) {
      short8 b0 = *(const short8*)&sH[wv][lm][ks * 32 + q * 8];
      #pragma unroll
      for (int dt = 0; dt < 8; ++dt) {
        short8 a = *(const short8*)&sW2[dt * 16 + lm][ks * 32 + q * 8];
        acc[dt] = __builtin_amdgcn_mfma_f32_16x16x32_bf16(a, b0, acc[dt], 0, 0, 0);
      }
    }
    __syncthreads();  // protect sW1/sW2 before next staging
  }

  // epilogue: float4 stores (top-1 softmax score == 1.0)
  if (i0 < cnt) {
    float* op = out + (size_t)grow * DD + q * 4;
    #pragma unroll
    for (int dt = 0; dt < 8; ++dt)
      *(f32x4*)(op + dt * 16) = acc[dt];
  }
}

extern "C" void kernel_launch(void* const* d_in, const int* in_sizes, int n_in,
                              void* d_out, int out_size, void* d_ws, size_t ws_size,
                              hipStream_t stream) {
  const float* x  = (const float*)d_in[0];
  const float* w1 = (const float*)d_in[1];
  const float* w2 = (const float*)d_in[2];
  const float* wg = (const float*)d_in[3];
  const float* bg = (const float*)d_in[4];
  float* out = (float*)d_out;

  // ws: [0,1024) counts padded 64B/expert | [1024,+2MB) rows | w1T 2MB | w2T 2MB
  int* counts = (int*)d_ws;               // counts[e] at int index e*16
  int* rows   = (int*)((char*)d_ws + 1024);
  unsigned short* w1T = (unsigned short*)((char*)d_ws + 1024 + (size_t)EE * NB * 4);
  unsigned short* w2T = w1T + (size_t)EE * HH * DD;

  hipMemsetAsync(d_ws, 0, 1024, stream);
  hipLaunchKernelGGL(prep_kernel, dim3(1024), dim3(256), 0, stream,
                     x, w1, w2, wg, bg, w1T, w2T, counts, rows);
  hipLaunchKernelGGL(moe_gemm, dim3(NB / 64, EE), dim3(256), 0, stream,
                     x, w1T, w2T, counts, rows, out);
}